// Round 11
// baseline (171.311 us; speedup 1.0000x reference)
//
#include <hip/hip_runtime.h>
#include <hip/hip_bf16.h>

#define EMBED 1024
#define HEADS 16
#define HD 64
#define NB 2
#define LSEQ 2048

typedef __bf16 bf16x8 __attribute__((ext_vector_type(8)));
typedef float f32x4 __attribute__((ext_vector_type(4)));

static __device__ __forceinline__ __bf16 f2b(float x) {
    union { __hip_bfloat16 h; __bf16 b; } u;
    u.h = __float2bfloat16(x);
    return u.b;
}
static __device__ __forceinline__ bf16x8 cvt8(float4 a, float4 b) {
    bf16x8 r;
    r[0] = f2b(a.x); r[1] = f2b(a.y); r[2] = f2b(a.z); r[3] = f2b(a.w);
    r[4] = f2b(b.x); r[5] = f2b(b.y); r[6] = f2b(b.z); r[7] = f2b(b.w);
    return r;
}
static __device__ __forceinline__ unsigned short b2u(float x) {
    union { __hip_bfloat16 h; unsigned short u; } c;
    c.h = __float2bfloat16(x);
    return c.u;
}

// async global->LDS, 16B per lane
#define GLD16(g, l) __builtin_amdgcn_global_load_lds( \
    (const __attribute__((address_space(1))) void*)(g), \
    (__attribute__((address_space(3))) void*)(l), 16, 0, 0)

// ---------------------------------------------------------------------------
// FRAGMENT-ORDER layouts (per nh, all 131072 bf16):
//  QF: [T=q/16][kk][lane=quad*16+(q&15)][j]  elem = Q[q][kk*32+quad*8+j]
//  KF: [c=key/32][t2*2+kk][lane=quad*16+j2][j] elem = K[c*32+2*j2+t2][kk*32+quad*8+j]
//  VF: [c][f=d/16][lane=quad*16+(d&15)][j]   elem = V[c*32+quad*8+j][f*16+(d&15)]
//      (i.e. V^T in A-fragment order: m=d, k=key)
// ---------------------------------------------------------------------------

// ---------------------------------------------------------------------------
// Kernel 1: QKV projection. TWO heads per block (grid 1536); X fragments for
// both heads loaded before any W load / MFMA. Fused Wo->bf16 conversion in
// blocks 1536..1791.  [FROZEN: round-6 exact]
// ---------------------------------------------------------------------------
__global__ __launch_bounds__(256) void proj_kernel(
    const float* __restrict__ vals,
    const float* __restrict__ keys,
    const float* __restrict__ quer,
    const float* __restrict__ Wv,
    const float* __restrict__ Wk,
    const float* __restrict__ Wq,
    const float* __restrict__ Wo,
    __hip_bfloat16* __restrict__ QF,
    __hip_bfloat16* __restrict__ KF,
    __hip_bfloat16* __restrict__ VF,
    __hip_bfloat16* __restrict__ Wob)
{
    if (blockIdx.x >= 1536) {   // fused wcvt: 256 blocks
        int base = ((blockIdx.x - 1536) * 256 + threadIdx.x) * 16;
#pragma unroll
        for (int j = 0; j < 16; j += 4) {
            float4 w4 = *(const float4*)(Wo + base + j);
            __hip_bfloat16 o[4] = {
                __float2bfloat16(w4.x), __float2bfloat16(w4.y),
                __float2bfloat16(w4.z), __float2bfloat16(w4.w)};
            *(ushort4*)(Wob + base + j) = *(const ushort4*)o;
        }
        return;
    }

    int b      = blockIdx.x;
    int tensor = b % 3;
    int rem    = b / 3;                 // [n(1) | lt(5) | hp(3)]
    int n      = rem >> 8;
    int lt     = (rem >> 3) & 31;
    int hp     = rem & 7;               // head pair
    int t = threadIdx.x, w = t >> 6, lane = t & 63;
    int m16 = lane & 15, quad = lane >> 4;
    int l0 = lt * 64 + w * 16;

    const float* X = (tensor == 0) ? quer : (tensor == 1 ? keys : vals);
    const float* W = (tensor == 0) ? Wq   : (tensor == 1 ? Wk   : Wv);
    float scale = (tensor == 0) ? (1.44269504088896340736f / 32.0f) : 1.0f;

    // X fragments for BOTH heads first (HBM, longest latency), then W (L2-hot)
    const float* xb = X + ((size_t)n * LSEQ + l0 + m16) * EMBED + (hp * 2) * HD + quad * 8;
    bf16x8 xf[2][2];
#pragma unroll
    for (int hh = 0; hh < 2; ++hh)
#pragma unroll
        for (int kk = 0; kk < 2; ++kk) {
            const float* xp = xb + hh * HD + kk * 32;
            xf[hh][kk] = cvt8(*(const float4*)xp, *(const float4*)(xp + 4));
        }

    bf16x8 wf[4][2];
#pragma unroll
    for (int f = 0; f < 4; ++f)
#pragma unroll
        for (int kk = 0; kk < 2; ++kk) {
            const float* wp = W + (f * 16 + m16) * HD + kk * 32 + quad * 8;
            wf[f][kk] = cvt8(*(const float4*)wp, *(const float4*)(wp + 4));
        }

#pragma unroll
    for (int hh = 0; hh < 2; ++hh) {
        int h = hp * 2 + hh;
        size_t nhb = (size_t)(n * HEADS + h) * 131072;
        if (tensor != 2) {
            // D = W·X^T: lane holds Y[e=f*16+quad*4+r][key/q = l0+m16]
            f32x4 acc[4] = {};
#pragma unroll
            for (int f = 0; f < 4; ++f) {
                acc[f] = __builtin_amdgcn_mfma_f32_16x16x32_bf16(wf[f][0], xf[hh][0], acc[f], 0, 0, 0);
                acc[f] = __builtin_amdgcn_mfma_f32_16x16x32_bf16(wf[f][1], xf[hh][1], acc[f], 0, 0, 0);
            }
            int key = l0 + m16;
#pragma unroll
            for (int f = 0; f < 4; ++f) {
                union { ushort4 u; unsigned short s[4]; } p;
#pragma unroll
                for (int r = 0; r < 4; ++r) p.s[r] = b2u(acc[f][r] * scale);
                int kk   = f >> 1;
                int qk2  = (f & 1) * 2 + (quad >> 1);   // d-quad in fragment
                int j4   = (quad & 1) * 4;              // d&7 base
                __hip_bfloat16* dst;
                if (tensor == 0) {
                    dst = QF + nhb + (size_t)(l0 >> 4) * 1024 + kk * 512
                        + (qk2 * 16 + m16) * 8 + j4;
                } else {
                    dst = KF + nhb + (size_t)(key >> 5) * 2048
                        + ((key & 1) * 2 + kk) * 512
                        + (qk2 * 16 + ((key & 31) >> 1)) * 8 + j4;
                }
                *(ushort4*)dst = p.u;
            }
        } else {
            // D = X·W^T: lane holds V[key = l0+quad*4+r][d = f*16+m16]
            f32x4 acc[4] = {};
#pragma unroll
            for (int f = 0; f < 4; ++f) {
                acc[f] = __builtin_amdgcn_mfma_f32_16x16x32_bf16(xf[hh][0], wf[f][0], acc[f], 0, 0, 0);
                acc[f] = __builtin_amdgcn_mfma_f32_16x16x32_bf16(xf[hh][1], wf[f][1], acc[f], 0, 0, 0);
            }
            int keyq  = l0 + quad * 4;
            int c     = keyq >> 5;
            int quadv = (keyq & 31) >> 3;
            int j4    = (quad & 1) * 4;
#pragma unroll
            for (int f = 0; f < 4; ++f) {
                union { ushort4 u; unsigned short s[4]; } p;
#pragma unroll
                for (int r = 0; r < 4; ++r) p.s[r] = b2u(acc[f][r]);
                __hip_bfloat16* dst = VF + nhb + (size_t)c * 2048 + f * 512
                    + quadv * 128 + m16 * 8 + j4;
                *(ushort4*)dst = p.u;
            }
        }
    }
}

// ---------------------------------------------------------------------------
// Kernel 2: flash attention v12 — LDS-staged K/V (T3+T4).
// The 4 waves cooperatively stage each chunk's 16 KB (K+V, both kh halves)
// into a double-buffered LDS region via global_load_lds w16: K/V cross L2
// ONCE per block (qh pair shares), halving L2 traffic (1 GB -> 512 MB).
// Counted vmcnt(4) keeps next-chunk loads in flight across barriers;
// PVX(c-1) (register-only) overlaps the ds_read latency. Swapped-MFMA
// in-register P, ones-MFMA denominator, setprio, 2-way split-K unchanged.
// ---------------------------------------------------------------------------

// wave w stages region w: 0=K.kh0 1=K.kh1 2=V.kh0 3=V.kh1 (4 KB each)
#define STAGE(b_, c_) do { \
    const __hip_bfloat16* s_ = gsrc + (size_t)(c_) * 2048; \
    GLD16(s_,        &SB[b_][wst]); \
    GLD16(s_ +  512, &SB[b_][wst + 1024]); \
    GLD16(s_ + 1024, &SB[b_][wst + 2048]); \
    GLD16(s_ + 1536, &SB[b_][wst + 3072]); \
} while (0)

// compute-side fragment reads: K at kh*4096, V at 8192+kh*4096 (bytes)
#define READKV(b_, VR) do { \
    const __hip_bfloat16* kb_ = (const __hip_bfloat16*)&SB[b_][kh * 4096 + lane * 16]; \
    kreg[0][0] = *(const bf16x8*)(kb_); \
    kreg[0][1] = *(const bf16x8*)(kb_ + 512); \
    kreg[1][0] = *(const bf16x8*)(kb_ + 1024); \
    kreg[1][1] = *(const bf16x8*)(kb_ + 1536); \
    const __hip_bfloat16* vb_ = kb_ + 4096; \
    VR[0] = *(const bf16x8*)(vb_); \
    VR[1] = *(const bf16x8*)(vb_ + 512); \
    VR[2] = *(const bf16x8*)(vb_ + 1024); \
    VR[3] = *(const bf16x8*)(vb_ + 1536); \
} while (0)

// S^T(c) = mfma(K, Q), exp2, pack into PF (B-fragment for PV)
#define SCOREX(KFR, PF) do { \
    f32x4 s_[2][2]; \
    __builtin_amdgcn_s_setprio(1); \
    _Pragma("unroll") \
    for (int tq_ = 0; tq_ < 2; ++tq_) { \
        _Pragma("unroll") \
        for (int t2_ = 0; t2_ < 2; ++t2_) { \
            f32x4 z_; \
            z_ = __builtin_amdgcn_mfma_f32_16x16x32_bf16(KFR[t2_][0], qf[tq_][0], zf, 0, 0, 0); \
            z_ = __builtin_amdgcn_mfma_f32_16x16x32_bf16(KFR[t2_][1], qf[tq_][1], z_, 0, 0, 0); \
            s_[tq_][t2_] = z_; \
        } \
    } \
    __builtin_amdgcn_s_setprio(0); \
    _Pragma("unroll") \
    for (int tq_ = 0; tq_ < 2; ++tq_) { \
        _Pragma("unroll") \
        for (int r_ = 0; r_ < 4; ++r_) { \
            PF[tq_][2 * r_]     = f2b(__builtin_amdgcn_exp2f(s_[tq_][0][r_])); \
            PF[tq_][2 * r_ + 1] = f2b(__builtin_amdgcn_exp2f(s_[tq_][1][r_])); \
        } \
    } \
} while (0)

// O^T += V^T · P^T ; ls += 1 · P^T   (all register operands)
#define PVX(PF, VFR) do { \
    __builtin_amdgcn_s_setprio(1); \
    _Pragma("unroll") \
    for (int f_ = 0; f_ < 4; ++f_) { \
        of[0][f_] = __builtin_amdgcn_mfma_f32_16x16x32_bf16(VFR[f_], PF[0], of[0][f_], 0, 0, 0); \
        of[1][f_] = __builtin_amdgcn_mfma_f32_16x16x32_bf16(VFR[f_], PF[1], of[1][f_], 0, 0, 0); \
    } \
    lsa[0] = __builtin_amdgcn_mfma_f32_16x16x32_bf16(onesf, PF[0], lsa[0], 0, 0, 0); \
    lsa[1] = __builtin_amdgcn_mfma_f32_16x16x32_bf16(onesf, PF[1], lsa[1], 0, 0, 0); \
    __builtin_amdgcn_s_setprio(0); \
} while (0)

// one pipeline iteration: stage(c+1), wait chunk c staged, read, overlap
// PVX(c-1), fence, score(c).  b_ = c&1 (compile-time), VN = v[c&1], VP = v[(c-1)&1]
#define ITER(b_, c_, VN, VP) do { \
    STAGE((b_) ^ 1, (c_) + 1); \
    asm volatile("s_waitcnt vmcnt(4)" ::: "memory"); \
    __builtin_amdgcn_s_barrier(); \
    READKV(b_, VN); \
    PVX(pP, VP); \
    __builtin_amdgcn_sched_barrier(0); \
    asm volatile("s_waitcnt lgkmcnt(0)" ::: "memory"); \
    __builtin_amdgcn_s_barrier(); \
    SCOREX(kreg, pP); \
} while (0)

__global__ __launch_bounds__(256) void attn_kernel(
    const __hip_bfloat16* __restrict__ QF,
    const __hip_bfloat16* __restrict__ KF,
    const __hip_bfloat16* __restrict__ VF,
    __hip_bfloat16* __restrict__ AO)
{
    __shared__ __align__(16) unsigned char SB[2][16384];   // 32 KB stage dbuf

    int i  = blockIdx.x;              // 1024
    int x  = i & 7, r2 = i >> 3;      // XCD swizzle: 4 heads pinned per XCD
    int nh = x * 4 + (r2 >> 5);       // 0..31
    int qblk = r2 & 31;

    int t = threadIdx.x, w = t >> 6, lane = t & 63;
    int m16 = lane & 15, quad = lane >> 4;
    int qh = w & 1, kh = w >> 1;
    int q0 = qblk * 64 + qh * 32;
    size_t nhb = (size_t)nh * 131072;

    // Q fragments: lane-contiguous from QF
    const __hip_bfloat16* qb = QF + nhb + (size_t)(q0 >> 4) * 1024 + lane * 8;
    bf16x8 qf[2][2];
#pragma unroll
    for (int tq = 0; tq < 2; ++tq)
#pragma unroll
        for (int kk = 0; kk < 2; ++kk)
            qf[tq][kk] = *(const bf16x8*)(qb + tq * 1024 + kk * 512);

    // staging role (independent of compute role): wave w stages region w
    const __hip_bfloat16* gsrc = (w < 2 ? KF : VF) + nhb
        + (size_t)((w & 1) * 32) * 2048 + (size_t)lane * 8;
    int wst = w * 4096;               // byte offset of wave's stage region

    bf16x8 onesf;
#pragma unroll
    for (int j = 0; j < 8; ++j) onesf[j] = f2b(1.0f);
    const f32x4 zf = {};   // persistent zero C-operand

    f32x4 of[2][4] = {};
    f32x4 lsa[2] = {};
    bf16x8 kreg[2][2], vA[4], vB[4], pP[2];

    // prologue: stage chunk 0, drain, publish
    STAGE(0, 0);
    asm volatile("s_waitcnt vmcnt(0)" ::: "memory");
    __builtin_amdgcn_s_barrier();

    // peeled iter 0 (no PVX)
    STAGE(1, 1);
    asm volatile("s_waitcnt vmcnt(4)" ::: "memory");
    __builtin_amdgcn_s_barrier();
    READKV(0, vA);
    __builtin_amdgcn_sched_barrier(0);
    asm volatile("s_waitcnt lgkmcnt(0)" ::: "memory");
    __builtin_amdgcn_s_barrier();
    SCOREX(kreg, pP);                 // P(0)

#pragma unroll 1
    for (int tt = 0; tt < 15; ++tt) {
        ITER(1, 2 * tt + 1, vB, vA);  // chunk 2tt+1: PVX(2tt),   SCOREX(2tt+1)
        ITER(0, 2 * tt + 2, vA, vB);  // chunk 2tt+2: PVX(2tt+1), SCOREX(2tt+2)
    }
    // peeled iter 31 (no stage -> drain own chunk-31 loads fully)
    asm volatile("s_waitcnt vmcnt(0)" ::: "memory");
    __builtin_amdgcn_s_barrier();
    READKV(1, vB);
    PVX(pP, vA);                      // chunk 30
    __builtin_amdgcn_sched_barrier(0);
    asm volatile("s_waitcnt lgkmcnt(0)" ::: "memory");
    SCOREX(kreg, pP);                 // P(31)
    PVX(pP, vB);                      // chunk 31

    // ---- 2-way split-K combine via LDS (reuse stage buffer) ----
    float* Cb = (float*)&SB[0][0];
    __syncthreads();
    if (kh == 1) {
        int base = qh * 2560;
#pragma unroll
        for (int tq = 0; tq < 2; ++tq)
#pragma unroll
            for (int f = 0; f < 4; ++f)
                *(f32x4*)&Cb[base + (tq * 4 + f) * 256 + lane * 4] = of[tq][f];
#pragma unroll
        for (int tq = 0; tq < 2; ++tq)
            Cb[base + 2048 + tq * 64 + lane] = lsa[tq][0];
    }
    __syncthreads();
    if (kh == 0) {
        int base = qh * 2560;
#pragma unroll
        for (int tq = 0; tq < 2; ++tq)
#pragma unroll
            for (int f = 0; f < 4; ++f)
                of[tq][f] += *(const f32x4*)&Cb[base + (tq * 4 + f) * 256 + lane * 4];
        int n = nh >> 4, h = nh & 15;
#pragma unroll
        for (int tq = 0; tq < 2; ++tq) {
            float lt2 = lsa[tq][0] + Cb[base + 2048 + tq * 64 + lane];
            float rinv = 1.0f / lt2;
            int qrow = q0 + tq * 16 + m16;
#pragma unroll
            for (int f = 0; f < 4; ++f) {
                union { ushort4 u; unsigned short s[4]; } pk;
#pragma unroll
                for (int r = 0; r < 4; ++r) pk.s[r] = b2u(of[tq][f][r] * rinv);
                int col = h * HD + f * 16 + quad * 4;
                *(ushort4*)&AO[((size_t)n * LSEQ + qrow) * EMBED + col] = pk.u;
            }
        }
    }
}

// ---------------------------------------------------------------------------
// Kernel 3: out = AO @ Wob^T + bo (fp32 out). [FROZEN: round-10 version —
// 64x64 tile, BK=64, counted-vmcnt double buffer, XCD-bijective swizzle]
// ---------------------------------------------------------------------------
__global__ __launch_bounds__(256) void outproj_kernel(
    const __hip_bfloat16* __restrict__ AO,
    const __hip_bfloat16* __restrict__ Wob,
    const float* __restrict__ bo,
    float* __restrict__ out)
{
    __shared__ __align__(16) __hip_bfloat16 As[2][2][64][32];  // 16 KB
    __shared__ __align__(16) __hip_bfloat16 Bs[2][2][64][32];  // 16 KB

    int b  = blockIdx.x;
    int wk = (b & 7) * 128 + (b >> 3);   // XCD-bijective: XCD c owns mt c*8..c*8+7
    int mt = wk >> 4, nt = wk & 15;      // 64 x 16 tiles
    int m0 = mt * 64, n0 = nt * 64;
    int t = threadIdx.x, w = t >> 6, lane = t & 63;
    int m16 = lane & 15, quad = lane >> 4;

    int srow = lane >> 2;        // 0..15
    int scol = (lane & 3) * 8;   // 0,8,16,24

    const __hip_bfloat16* Ab = AO  + (size_t)m0 * EMBED;
    const __hip_bfloat16* Bb = Wob + (size_t)n0 * EMBED;

#define STAGE_OP(bb, k0_) do { \
    GLD16(Ab + (size_t)(w * 16 + srow) * EMBED + (k0_) +      scol, &As[bb][0][w * 16][0]); \
    GLD16(Ab + (size_t)(w * 16 + srow) * EMBED + (k0_) + 32 + scol, &As[bb][1][w * 16][0]); \
    GLD16(Bb + (size_t)(w * 16 + srow) * EMBED + (k0_) +      scol, &Bs[bb][0][w * 16][0]); \
    GLD16(Bb + (size_t)(w * 16 + srow) * EMBED + (k0_) + 32 + scol, &Bs[bb][1][w * 16][0]); \
} while (0)

    f32x4 acc[4] = {};
    STAGE_OP(0, 0);

#pragma unroll 1
    for (int ks = 0; ks < 16; ++ks) {
        int cur = ks & 1;
        if (ks < 15) {
            STAGE_OP(cur ^ 1, (ks + 1) * 64);                  // issue next tile
            asm volatile("s_waitcnt vmcnt(4)" ::: "memory");   // cur done, next in flight
        } else {
            asm volatile("s_waitcnt vmcnt(0)" ::: "memory");   // epilogue drain
        }
        __builtin_amdgcn_s_barrier();                          // all waves: cur complete

        bf16x8 af[2], bfr[2][4];
#pragma unroll
        for (int kk = 0; kk < 2; ++kk)
            af[kk] = *(const bf16x8*)&As[cur][kk][w * 16 + m16][quad * 8];
#pragma unroll
        for (int kk = 0; kk < 2; ++kk)
#pragma unroll
            for (int tb = 0; tb < 4; ++tb)
                bfr[kk][tb] = *(const bf16x8*)&Bs[cur][kk][tb * 16 + m16][quad * 8];
        asm volatile("s_waitcnt lgkmcnt(0)" ::: "memory");     // reads landed
        __builtin_amdgcn_s_barrier();                          // cur released

#pragma unroll
        for (int tb = 0; tb < 4; ++tb) {
            acc[tb] = __builtin_amdgcn_mfma_f32_16x16x32_bf16(af[0], bfr[0][tb], acc[tb], 0, 0, 0);
            acc[tb] = __builtin_amdgcn_mfma_f32_16x16x32_bf16(af[1], bfr[1][tb], acc[tb], 0, 0, 0);
        }
    }

#pragma unroll
    for (int tb = 0; tb < 4; ++tb) {
        int col = n0 + tb * 16 + m16;
        float bias = bo[col];
#pragma unroll
        for (int r = 0; r < 4; ++r) {
            int row = m0 + w * 16 + quad * 4 + r;
            out[(size_t)row * EMBED + col] = acc[tb][r] + bias;
        }
    }
#undef STAGE_OP
}

// ---------------------------------------------------------------------------
extern "C" void kernel_launch(void* const* d_in, const int* in_sizes, int n_in,
                              void* d_out, int out_size, void* d_ws, size_t ws_size,
                              hipStream_t stream) {
    const float* vals = (const float*)d_in[0];
    const float* keys = (const float*)d_in[1];
    const float* quer = (const float*)d_in[2];
    const float* Wv   = (const float*)d_in[3];
    const float* Wk   = (const float*)d_in[4];
    const float* Wq   = (const float*)d_in[5];
    const float* Wo   = (const float*)d_in[6];
    const float* bo   = (const float*)d_in[7];
    float* out = (float*)d_out;

    __hip_bfloat16* ws = (__hip_bfloat16*)d_ws;
    const size_t PE = (size_t)NB * HEADS * LSEQ * HD;   // 4,194,304
    __hip_bfloat16* QF  = ws;
    __hip_bfloat16* KF  = ws + PE;
    __hip_bfloat16* VF  = ws + 2 * PE;
    __hip_bfloat16* AO  = ws + 3 * PE;
    __hip_bfloat16* Wob = ws + 4 * PE;

    proj_kernel<<<1536 + 256, 256, 0, stream>>>(
        vals, keys, quer, Wv, Wk, Wq, Wo, QF, KF, VF, Wob);
    attn_kernel<<<1024, 256, 0, stream>>>(QF, KF, VF, AO);
    outproj_kernel<<<1024, 256, 0, stream>>>(AO, Wob, bo, out);
}

// Round 13
// 167.658 us; speedup vs baseline: 1.0218x; 1.0218x over previous
//
#include <hip/hip_runtime.h>
#include <hip/hip_bf16.h>

#define EMBED 1024
#define HEADS 16
#define HD 64
#define NB 2
#define LSEQ 2048

typedef __bf16 bf16x8 __attribute__((ext_vector_type(8)));
typedef float f32x4 __attribute__((ext_vector_type(4)));

static __device__ __forceinline__ __bf16 f2b(float x) {
    union { __hip_bfloat16 h; __bf16 b; } u;
    u.h = __float2bfloat16(x);
    return u.b;
}
static __device__ __forceinline__ bf16x8 cvt8(float4 a, float4 b) {
    bf16x8 r;
    r[0] = f2b(a.x); r[1] = f2b(a.y); r[2] = f2b(a.z); r[3] = f2b(a.w);
    r[4] = f2b(b.x); r[5] = f2b(b.y); r[6] = f2b(b.z); r[7] = f2b(b.w);
    return r;
}
static __device__ __forceinline__ unsigned short b2u(float x) {
    union { __hip_bfloat16 h; unsigned short u; } c;
    c.h = __float2bfloat16(x);
    return c.u;
}

// async global->LDS, 16B per lane
#define GLD16(g, l) __builtin_amdgcn_global_load_lds( \
    (const __attribute__((address_space(1))) void*)(g), \
    (__attribute__((address_space(3))) void*)(l), 16, 0, 0)

// ---------------------------------------------------------------------------
// FRAGMENT-ORDER layouts (per nh, all 131072 bf16):
//  QF: [T=q/16][kk][lane=quad*16+(q&15)][j]  elem = Q[q][kk*32+quad*8+j]
//  KF: [c=key/32][t2*2+kk][lane=quad*16+j2][j] elem = K[c*32+2*j2+t2][kk*32+quad*8+j]
//  VF: [c][f=d/16][lane=quad*16+(d&15)][j]   elem = V[c*32+quad*8+j][f*16+(d&15)]
//      (i.e. V^T in A-fragment order: m=d, k=key)
// ---------------------------------------------------------------------------

// ---------------------------------------------------------------------------
// Kernel 1: QKV projection. TWO heads per block (grid 1536); X fragments for
// both heads loaded before any W load / MFMA. Fused Wo->bf16 conversion in
// blocks 1536..1791.  [FROZEN: round-6 exact]
// ---------------------------------------------------------------------------
__global__ __launch_bounds__(256) void proj_kernel(
    const float* __restrict__ vals,
    const float* __restrict__ keys,
    const float* __restrict__ quer,
    const float* __restrict__ Wv,
    const float* __restrict__ Wk,
    const float* __restrict__ Wq,
    const float* __restrict__ Wo,
    __hip_bfloat16* __restrict__ QF,
    __hip_bfloat16* __restrict__ KF,
    __hip_bfloat16* __restrict__ VF,
    __hip_bfloat16* __restrict__ Wob)
{
    if (blockIdx.x >= 1536) {   // fused wcvt: 256 blocks
        int base = ((blockIdx.x - 1536) * 256 + threadIdx.x) * 16;
#pragma unroll
        for (int j = 0; j < 16; j += 4) {
            float4 w4 = *(const float4*)(Wo + base + j);
            __hip_bfloat16 o[4] = {
                __float2bfloat16(w4.x), __float2bfloat16(w4.y),
                __float2bfloat16(w4.z), __float2bfloat16(w4.w)};
            *(ushort4*)(Wob + base + j) = *(const ushort4*)o;
        }
        return;
    }

    int b      = blockIdx.x;
    int tensor = b % 3;
    int rem    = b / 3;                 // [n(1) | lt(5) | hp(3)]
    int n      = rem >> 8;
    int lt     = (rem >> 3) & 31;
    int hp     = rem & 7;               // head pair
    int t = threadIdx.x, w = t >> 6, lane = t & 63;
    int m16 = lane & 15, quad = lane >> 4;
    int l0 = lt * 64 + w * 16;

    const float* X = (tensor == 0) ? quer : (tensor == 1 ? keys : vals);
    const float* W = (tensor == 0) ? Wq   : (tensor == 1 ? Wk   : Wv);
    float scale = (tensor == 0) ? (1.44269504088896340736f / 32.0f) : 1.0f;

    // X fragments for BOTH heads first (HBM, longest latency), then W (L2-hot)
    const float* xb = X + ((size_t)n * LSEQ + l0 + m16) * EMBED + (hp * 2) * HD + quad * 8;
    bf16x8 xf[2][2];
#pragma unroll
    for (int hh = 0; hh < 2; ++hh)
#pragma unroll
        for (int kk = 0; kk < 2; ++kk) {
            const float* xp = xb + hh * HD + kk * 32;
            xf[hh][kk] = cvt8(*(const float4*)xp, *(const float4*)(xp + 4));
        }

    bf16x8 wf[4][2];
#pragma unroll
    for (int f = 0; f < 4; ++f)
#pragma unroll
        for (int kk = 0; kk < 2; ++kk) {
            const float* wp = W + (f * 16 + m16) * HD + kk * 32 + quad * 8;
            wf[f][kk] = cvt8(*(const float4*)wp, *(const float4*)(wp + 4));
        }

#pragma unroll
    for (int hh = 0; hh < 2; ++hh) {
        int h = hp * 2 + hh;
        size_t nhb = (size_t)(n * HEADS + h) * 131072;
        if (tensor != 2) {
            // D = W·X^T: lane holds Y[e=f*16+quad*4+r][key/q = l0+m16]
            f32x4 acc[4] = {};
#pragma unroll
            for (int f = 0; f < 4; ++f) {
                acc[f] = __builtin_amdgcn_mfma_f32_16x16x32_bf16(wf[f][0], xf[hh][0], acc[f], 0, 0, 0);
                acc[f] = __builtin_amdgcn_mfma_f32_16x16x32_bf16(wf[f][1], xf[hh][1], acc[f], 0, 0, 0);
            }
            int key = l0 + m16;
#pragma unroll
            for (int f = 0; f < 4; ++f) {
                union { ushort4 u; unsigned short s[4]; } p;
#pragma unroll
                for (int r = 0; r < 4; ++r) p.s[r] = b2u(acc[f][r] * scale);
                int kk   = f >> 1;
                int qk2  = (f & 1) * 2 + (quad >> 1);   // d-quad in fragment
                int j4   = (quad & 1) * 4;              // d&7 base
                __hip_bfloat16* dst;
                if (tensor == 0) {
                    dst = QF + nhb + (size_t)(l0 >> 4) * 1024 + kk * 512
                        + (qk2 * 16 + m16) * 8 + j4;
                } else {
                    dst = KF + nhb + (size_t)(key >> 5) * 2048
                        + ((key & 1) * 2 + kk) * 512
                        + (qk2 * 16 + ((key & 31) >> 1)) * 8 + j4;
                }
                *(ushort4*)dst = p.u;
            }
        } else {
            // D = X·W^T: lane holds V[key = l0+quad*4+r][d = f*16+m16]
            f32x4 acc[4] = {};
#pragma unroll
            for (int f = 0; f < 4; ++f) {
                acc[f] = __builtin_amdgcn_mfma_f32_16x16x32_bf16(xf[hh][0], wf[f][0], acc[f], 0, 0, 0);
                acc[f] = __builtin_amdgcn_mfma_f32_16x16x32_bf16(xf[hh][1], wf[f][1], acc[f], 0, 0, 0);
            }
            int keyq  = l0 + quad * 4;
            int c     = keyq >> 5;
            int quadv = (keyq & 31) >> 3;
            int j4    = (quad & 1) * 4;
#pragma unroll
            for (int f = 0; f < 4; ++f) {
                union { ushort4 u; unsigned short s[4]; } p;
#pragma unroll
                for (int r = 0; r < 4; ++r) p.s[r] = b2u(acc[f][r]);
                __hip_bfloat16* dst = VF + nhb + (size_t)c * 2048 + f * 512
                    + quadv * 128 + m16 * 8 + j4;
                *(ushort4*)dst = p.u;
            }
        }
    }
}

// ---------------------------------------------------------------------------
// Kernel 2: flash attention v8 [FROZEN: round-6 exact, best measured 48.0us].
// In-register P via swapped MFMA; 1024 blocks, 2-way split-K; ones-MFMA
// denominator; setprio; libcall bf16 converts (RNE).
// ---------------------------------------------------------------------------
#define CHUNKS 32

#define LOADK(KFR, c_) do { \
    const __hip_bfloat16* kc_ = kp + (size_t)(c_) * 2048; \
    KFR[0][0] = *(const bf16x8*)(kc_); \
    KFR[0][1] = *(const bf16x8*)(kc_ + 512); \
    KFR[1][0] = *(const bf16x8*)(kc_ + 1024); \
    KFR[1][1] = *(const bf16x8*)(kc_ + 1536); \
} while (0)

#define LOADV(c_) do { \
    const __hip_bfloat16* vc_ = vp + (size_t)(c_) * 2048; \
    vf[0] = *(const bf16x8*)(vc_); \
    vf[1] = *(const bf16x8*)(vc_ + 512); \
    vf[2] = *(const bf16x8*)(vc_ + 1024); \
    vf[3] = *(const bf16x8*)(vc_ + 1536); \
} while (0)

// S^T(c) = mfma(K, Q), exp2, pack into PF (B-fragment for PV)
#define SCOREX(KFR, PF) do { \
    f32x4 s_[2][2]; \
    __builtin_amdgcn_s_setprio(1); \
    _Pragma("unroll") \
    for (int tq_ = 0; tq_ < 2; ++tq_) { \
        _Pragma("unroll") \
        for (int t2_ = 0; t2_ < 2; ++t2_) { \
            f32x4 z_; \
            z_ = __builtin_amdgcn_mfma_f32_16x16x32_bf16(KFR[t2_][0], qf[tq_][0], zf, 0, 0, 0); \
            z_ = __builtin_amdgcn_mfma_f32_16x16x32_bf16(KFR[t2_][1], qf[tq_][1], z_, 0, 0, 0); \
            s_[tq_][t2_] = z_; \
        } \
    } \
    __builtin_amdgcn_s_setprio(0); \
    _Pragma("unroll") \
    for (int tq_ = 0; tq_ < 2; ++tq_) { \
        _Pragma("unroll") \
        for (int r_ = 0; r_ < 4; ++r_) { \
            PF[tq_][2 * r_]     = f2b(__builtin_amdgcn_exp2f(s_[tq_][0][r_])); \
            PF[tq_][2 * r_ + 1] = f2b(__builtin_amdgcn_exp2f(s_[tq_][1][r_])); \
        } \
    } \
} while (0)

// O^T += V^T · P^T ; ls += 1 · P^T
#define PVX(PF) do { \
    __builtin_amdgcn_s_setprio(1); \
    _Pragma("unroll") \
    for (int f_ = 0; f_ < 4; ++f_) { \
        of[0][f_] = __builtin_amdgcn_mfma_f32_16x16x32_bf16(vf[f_], PF[0], of[0][f_], 0, 0, 0); \
        of[1][f_] = __builtin_amdgcn_mfma_f32_16x16x32_bf16(vf[f_], PF[1], of[1][f_], 0, 0, 0); \
    } \
    lsa[0] = __builtin_amdgcn_mfma_f32_16x16x32_bf16(onesf, PF[0], lsa[0], 0, 0, 0); \
    lsa[1] = __builtin_amdgcn_mfma_f32_16x16x32_bf16(onesf, PF[1], lsa[1], 0, 0, 0); \
    __builtin_amdgcn_s_setprio(0); \
} while (0)

__global__ __launch_bounds__(256) void attn_kernel(
    const __hip_bfloat16* __restrict__ QF,
    const __hip_bfloat16* __restrict__ KF,
    const __hip_bfloat16* __restrict__ VF,
    __hip_bfloat16* __restrict__ AO)
{
    __shared__ __align__(16) float Cb[5120];   // 20 KB split-K combine

    int i  = blockIdx.x;              // 1024
    int x  = i & 7, r2 = i >> 3;      // XCD swizzle: 4 heads pinned per XCD
    int nh = x * 4 + (r2 >> 5);       // 0..31
    int qblk = r2 & 31;

    int t = threadIdx.x, w = t >> 6, lane = t & 63;
    int m16 = lane & 15, quad = lane >> 4;
    int qh = w & 1, kh = w >> 1;
    int q0 = qblk * 64 + qh * 32;
    size_t nhb = (size_t)nh * 131072;

    // Q fragments: lane-contiguous from QF
    const __hip_bfloat16* qb = QF + nhb + (size_t)(q0 >> 4) * 1024 + lane * 8;
    bf16x8 qf[2][2];
#pragma unroll
    for (int tq = 0; tq < 2; ++tq)
#pragma unroll
        for (int kk = 0; kk < 2; ++kk)
            qf[tq][kk] = *(const bf16x8*)(qb + tq * 1024 + kk * 512);

    const __hip_bfloat16* kp = KF + nhb + (size_t)(kh * 32) * 2048 + lane * 8;
    const __hip_bfloat16* vp = VF + nhb + (size_t)(kh * 32) * 2048 + lane * 8;

    bf16x8 onesf;
#pragma unroll
    for (int j = 0; j < 8; ++j) onesf[j] = f2b(1.0f);
    const f32x4 zf = {};   // persistent zero C-operand

    f32x4 of[2][4] = {};
    f32x4 lsa[2] = {};
    bf16x8 ka[2][2], kb[2][2], vf[4], pA[2], pB[2];

    // prologue: chunk 0
    LOADK(ka, 0);
    LOADK(kb, 1);
    SCOREX(ka, pA);          // P(0) in-register
    LOADV(0);

#pragma unroll 1
    for (int tt = 0; tt < 15; ++tt) {
        int c = 2 * tt;
        LOADK(ka, c + 2);
        SCOREX(kb, pB);      // P(c+1)   (K(c+1) loaded a full chunk ago)
        PVX(pA);             // P(c)·V(c), vf = V(c)
        LOADV(c + 1);
        LOADK(kb, c + 3);
        SCOREX(ka, pA);      // P(c+2)
        PVX(pB);             // P(c+1)·V(c+1)
        LOADV(c + 2);
    }
    // chunks 0..30 scored, PV 0..29 done, vf = V(30), pA = P(30)
    SCOREX(kb, pB);          // P(31)
    PVX(pA);                 // P(30)·V(30)
    LOADV(31);
    PVX(pB);                 // P(31)·V(31)

    // ---- 2-way split-K combine via LDS ----
    // of[tq][f]: lane m16 = q (within tq tile), rows quad*4+r = d&15.
    // lsa[tq][*] identical over rows; per-lane value is ls for q = m16.
    __syncthreads();
    if (kh == 1) {
        int base = qh * 2560;
#pragma unroll
        for (int tq = 0; tq < 2; ++tq)
#pragma unroll
            for (int f = 0; f < 4; ++f)
                *(f32x4*)&Cb[base + (tq * 4 + f) * 256 + lane * 4] = of[tq][f];
#pragma unroll
        for (int tq = 0; tq < 2; ++tq)
            Cb[base + 2048 + tq * 64 + lane] = lsa[tq][0];
    }
    __syncthreads();
    if (kh == 0) {
        int base = qh * 2560;
#pragma unroll
        for (int tq = 0; tq < 2; ++tq)
#pragma unroll
            for (int f = 0; f < 4; ++f)
                of[tq][f] += *(const f32x4*)&Cb[base + (tq * 4 + f) * 256 + lane * 4];
        int n = nh >> 4, h = nh & 15;
#pragma unroll
        for (int tq = 0; tq < 2; ++tq) {
            float lt2 = lsa[tq][0] + Cb[base + 2048 + tq * 64 + lane];
            float rinv = 1.0f / lt2;
            int qrow = q0 + tq * 16 + m16;
#pragma unroll
            for (int f = 0; f < 4; ++f) {
                union { ushort4 u; unsigned short s[4]; } pk;
#pragma unroll
                for (int r = 0; r < 4; ++r) pk.s[r] = b2u(of[tq][f][r] * rinv);
                int col = h * HD + f * 16 + quad * 4;
                *(ushort4*)&AO[((size_t)n * LSEQ + qrow) * EMBED + col] = pk.u;
            }
        }
    }
}

// ---------------------------------------------------------------------------
// Kernel 3: out = AO @ Wob^T + bo (fp32 out).
// [FROZEN: round-10 version — 64x64 tile, BK=64, counted-vmcnt double
// buffer (vmcnt(4) keeps next-tile loads in flight across barriers),
// XCD-bijective swizzle]
// ---------------------------------------------------------------------------
__global__ __launch_bounds__(256) void outproj_kernel(
    const __hip_bfloat16* __restrict__ AO,
    const __hip_bfloat16* __restrict__ Wob,
    const float* __restrict__ bo,
    float* __restrict__ out)
{
    __shared__ __align__(16) __hip_bfloat16 As[2][2][64][32];  // 16 KB
    __shared__ __align__(16) __hip_bfloat16 Bs[2][2][64][32];  // 16 KB

    int b  = blockIdx.x;
    int wk = (b & 7) * 128 + (b >> 3);   // XCD-bijective: XCD c owns mt c*8..c*8+7
    int mt = wk >> 4, nt = wk & 15;      // 64 x 16 tiles
    int m0 = mt * 64, n0 = nt * 64;
    int t = threadIdx.x, w = t >> 6, lane = t & 63;
    int m16 = lane & 15, quad = lane >> 4;

    int srow = lane >> 2;        // 0..15
    int scol = (lane & 3) * 8;   // 0,8,16,24

    const __hip_bfloat16* Ab = AO  + (size_t)m0 * EMBED;
    const __hip_bfloat16* Bb = Wob + (size_t)n0 * EMBED;

#define STAGE_OP(bb, k0_) do { \
    GLD16(Ab + (size_t)(w * 16 + srow) * EMBED + (k0_) +      scol, &As[bb][0][w * 16][0]); \
    GLD16(Ab + (size_t)(w * 16 + srow) * EMBED + (k0_) + 32 + scol, &As[bb][1][w * 16][0]); \
    GLD16(Bb + (size_t)(w * 16 + srow) * EMBED + (k0_) +      scol, &Bs[bb][0][w * 16][0]); \
    GLD16(Bb + (size_t)(w * 16 + srow) * EMBED + (k0_) + 32 + scol, &Bs[bb][1][w * 16][0]); \
} while (0)

    f32x4 acc[4] = {};
    STAGE_OP(0, 0);

#pragma unroll 1
    for (int ks = 0; ks < 16; ++ks) {
        int cur = ks & 1;
        if (ks < 15) {
            STAGE_OP(cur ^ 1, (ks + 1) * 64);                  // issue next tile
            asm volatile("s_waitcnt vmcnt(4)" ::: "memory");   // cur done, next in flight
        } else {
            asm volatile("s_waitcnt vmcnt(0)" ::: "memory");   // epilogue drain
        }
        __builtin_amdgcn_s_barrier();                          // all waves: cur complete

        bf16x8 af[2], bfr[2][4];
#pragma unroll
        for (int kk = 0; kk < 2; ++kk)
            af[kk] = *(const bf16x8*)&As[cur][kk][w * 16 + m16][quad * 8];
#pragma unroll
        for (int kk = 0; kk < 2; ++kk)
#pragma unroll
            for (int tb = 0; tb < 4; ++tb)
                bfr[kk][tb] = *(const bf16x8*)&Bs[cur][kk][tb * 16 + m16][quad * 8];
        asm volatile("s_waitcnt lgkmcnt(0)" ::: "memory");     // reads landed
        __builtin_amdgcn_s_barrier();                          // cur released

#pragma unroll
        for (int tb = 0; tb < 4; ++tb) {
            acc[tb] = __builtin_amdgcn_mfma_f32_16x16x32_bf16(af[0], bfr[0][tb], acc[tb], 0, 0, 0);
            acc[tb] = __builtin_amdgcn_mfma_f32_16x16x32_bf16(af[1], bfr[1][tb], acc[tb], 0, 0, 0);
        }
    }

#pragma unroll
    for (int tb = 0; tb < 4; ++tb) {
        int col = n0 + tb * 16 + m16;
        float bias = bo[col];
#pragma unroll
        for (int r = 0; r < 4; ++r) {
            int row = m0 + w * 16 + quad * 4 + r;
            out[(size_t)row * EMBED + col] = acc[tb][r] + bias;
        }
    }
#undef STAGE_OP
}

// ---------------------------------------------------------------------------
extern "C" void kernel_launch(void* const* d_in, const int* in_sizes, int n_in,
                              void* d_out, int out_size, void* d_ws, size_t ws_size,
                              hipStream_t stream) {
    const float* vals = (const float*)d_in[0];
    const float* keys = (const float*)d_in[1];
    const float* quer = (const float*)d_in[2];
    const float* Wv   = (const float*)d_in[3];
    const float* Wk   = (const float*)d_in[4];
    const float* Wq   = (const float*)d_in[5];
    const float* Wo   = (const float*)d_in[6];
    const float* bo   = (const float*)d_in[7];
    float* out = (float*)d_out;

    __hip_bfloat16* ws = (__hip_bfloat16*)d_ws;
    const size_t PE = (size_t)NB * HEADS * LSEQ * HD;   // 4,194,304
    __hip_bfloat16* QF  = ws;
    __hip_bfloat16* KF  = ws + PE;
    __hip_bfloat16* VF  = ws + 2 * PE;
    __hip_bfloat16* AO  = ws + 3 * PE;
    __hip_bfloat16* Wob = ws + 4 * PE;

    proj_kernel<<<1536 + 256, 256, 0, stream>>>(
        vals, keys, quer, Wv, Wk, Wq, Wo, QF, KF, VF, Wob);
    attn_kernel<<<1024, 256, 0, stream>>>(QF, KF, VF, AO);
    outproj_kernel<<<1024, 256, 0, stream>>>(AO, Wob, bo, out);
}